// Round 7
// baseline (607.102 us; speedup 1.0000x reference)
//
#include <hip/hip_runtime.h>
#include <hip/hip_fp16.h>

#define NB 256      // batch
#define NT 1024     // time
#define ND 64       // input dim
#define NH 128      // hidden dim

typedef __fp16 half8 __attribute__((ext_vector_type(8)));
typedef __fp16 half4v __attribute__((ext_vector_type(4)));
typedef __fp16 half2v __attribute__((ext_vector_type(2)));
typedef float float4v __attribute__((ext_vector_type(4)));

static __device__ __forceinline__ float fast_tanh(float v) {
    float e = __expf(2.0f * v);
    return 1.0f - 2.0f * __builtin_amdgcn_rcpf(e + 1.0f);
}

static __device__ __forceinline__ float fdot2f(half2v a, half2v b, float c) {
#if __has_builtin(__builtin_amdgcn_fdot2)
    return __builtin_amdgcn_fdot2(a, b, c, false);
#else
    return c + (float)a.x * (float)b.x + (float)a.y * (float)b.y;
#endif
}

// lgkm-only barrier: does NOT drain vmcnt (stores / x prefetch keep flying)
static __device__ __forceinline__ void fast_barrier() {
    asm volatile("s_waitcnt lgkmcnt(0)\n\ts_barrier" ::: "memory");
}

static __device__ __forceinline__ float dpp_xor1_add(float x) {
#if __has_builtin(__builtin_amdgcn_mov_dpp)
    int o = __builtin_amdgcn_mov_dpp(__builtin_bit_cast(int, x), 0xB1, 0xF, 0xF, true);
    return x + __builtin_bit_cast(float, o);
#else
    return x + __shfl_xor(x, 1);
#endif
}

static __device__ __forceinline__ float dpp_xor2_add(float x) {
#if __has_builtin(__builtin_amdgcn_mov_dpp)
    int o = __builtin_amdgcn_mov_dpp(__builtin_bit_cast(int, x), 0x4E, 0xF, 0xF, true);
    return x + __builtin_bit_cast(float, o);
#else
    return x + __shfl_xor(x, 2);
#endif
}

// 4 waves (1/SIMD), block = batch. Wave w owns hidden units [32w, 32w+32):
// both for the recurrence (lane quads: q=(tid>>2)&15, kh=tid&3 -> j0=32w+q,
// j1=j0+16; 32-elem k-slice per lane; DPP xor1+xor2 reduce) and for the
// chunk projection (same wave writes the gT/zT columns it later reads ->
// proj is barrier-free). Recurrence dot on VALU (fdot2): ~75cy/SIMD vs
// ~170cy for the 8-MFMA broadcast form (per-SIMD MFMA issue ~19cy, from
// r4/r5 counters). Only sync: one lgkm barrier per step for the h exchange.
// g/z staged TRANSPOSED [col][s] (stride 24 fp16, rows 48B -> 16B-aligned)
// so a lane's whole chunk is 8x ds_read_b128; proj epilogue writes b64.
// Outputs buffered in regs and burst-flushed per chunk (off the step chain).
__global__ __launch_bounds__(256, 1) void fused_rnn_v7(
        const float* __restrict__ x,
        const float* __restrict__ WxK, const float* __restrict__ bxK,
        const float* __restrict__ Wxz, const float* __restrict__ bxz,
        const float* __restrict__ Whk, const float* __restrict__ bhk,
        float* __restrict__ out) {
    __shared__ __align__(16) __fp16 hbuf[2][128];      // h fp16, dbuf per step parity
    __shared__ __align__(16) __fp16 gT[2][128][24];    // (gxK+bxK+bhK)^T per chunk: [col][s]
    __shared__ __align__(16) __fp16 zT[2][128][24];    // tanh(gxz+bxz)^T per chunk

    const int tid = threadIdx.x;
    const int b = blockIdx.x;
    const int w = tid >> 6, lane = tid & 63;
    const int l16 = lane & 15, kg = lane >> 4;
    const int q = (tid >> 2) & 15, kh = tid & 3;
    const int j0 = w * 32 + q, j1 = j0 + 16;   // this lane's two hidden units

    // ---- W_hK rows j0,j1, k-slice [32kh, 32kh+32), packed fp16 (32 VGPRs) ----
    half2v w0[16], w1[16];
    {
        const float4v* p0 = (const float4v*)(Whk + (size_t)j0 * NH + kh * 32);
        const float4v* p1 = (const float4v*)(Whk + (size_t)j1 * NH + kh * 32);
        #pragma unroll
        for (int i = 0; i < 8; ++i) {
            float4v v0 = p0[i], v1 = p1[i];
            w0[2 * i]     = __builtin_amdgcn_cvt_pkrtz(v0.x, v0.y);
            w0[2 * i + 1] = __builtin_amdgcn_cvt_pkrtz(v0.z, v0.w);
            w1[2 * i]     = __builtin_amdgcn_cvt_pkrtz(v1.x, v1.y);
            w1[2 * i + 1] = __builtin_amdgcn_cvt_pkrtz(v1.z, v1.w);
        }
    }

    // ---- proj B-fragments resident in VGPRs (cols [32w, 32w+32)) ----
    half8 wxT[2][2][2];   // [mat][ct][kt]
    float bGK[2], bZ[2];
    #pragma unroll
    for (int ct = 0; ct < 2; ++ct) {
        const int row = w * 32 + ct * 16 + l16;
        #pragma unroll
        for (int mat = 0; mat < 2; ++mat) {
            const float* W = mat ? Wxz : WxK;
            #pragma unroll
            for (int kt = 0; kt < 2; ++kt) {
                const float* p = W + (size_t)row * ND + kt * 32 + kg * 8;
                float4v u = *(const float4v*)p, v = *(const float4v*)(p + 4);
                wxT[mat][ct][kt] = (half8){(__fp16)u.x, (__fp16)u.y, (__fp16)u.z, (__fp16)u.w,
                                           (__fp16)v.x, (__fp16)v.y, (__fp16)v.z, (__fp16)v.w};
            }
        }
        bGK[ct] = bxK[row] + bhk[row];    // fold bhK into the staged gate
        bZ[ct]  = bxz[row];
    }
    const float4v zero4 = {0.f, 0.f, 0.f, 0.f};

    const float* xb = x + (size_t)b * NT * ND;
    float4v xf[4];    // prefetched x chunk A-fragments (f32)

    auto xload = [&](int c) {
        const float* px = xb + (size_t)c * 16 * 64 + (size_t)l16 * 64;
        #pragma unroll
        for (int kt = 0; kt < 2; ++kt) {
            const float* qp = px + kt * 32 + kg * 8;
            xf[2 * kt]     = *(const float4v*)qp;
            xf[2 * kt + 1] = *(const float4v*)(qp + 4);
        }
    };

    // project staged chunk into this wave's 32 cols of gT/zT[dst] (transposed):
    // 8 MFMAs + 4 packed b64 writes + 8 tanh. Barrier-free (same-wave use).
    auto proj = [&](int dst) {
        half8 ax[2];
        #pragma unroll
        for (int kt = 0; kt < 2; ++kt) {
            float4v u = xf[2 * kt], v = xf[2 * kt + 1];
            ax[kt] = (half8){(__fp16)u.x, (__fp16)u.y, (__fp16)u.z, (__fp16)u.w,
                             (__fp16)v.x, (__fp16)v.y, (__fp16)v.z, (__fp16)v.w};
        }
        #pragma unroll
        for (int ct = 0; ct < 2; ++ct) {
            const int col = w * 32 + ct * 16 + l16;
            // mat 0: gxK (+ folded biases)
            float4v pg = __builtin_amdgcn_mfma_f32_16x16x32_f16(ax[0], wxT[0][ct][0], zero4, 0, 0, 0);
            pg = __builtin_amdgcn_mfma_f32_16x16x32_f16(ax[1], wxT[0][ct][1], pg, 0, 0, 0);
            half4v hg = {(__fp16)(pg[0] + bGK[ct]), (__fp16)(pg[1] + bGK[ct]),
                         (__fp16)(pg[2] + bGK[ct]), (__fp16)(pg[3] + bGK[ct])};
            *(half4v*)&gT[dst][col][kg * 4] = hg;      // rows kg*4..+4 of col (b64)
            // mat 1: z = tanh(gxz + bxz)
            float4v pz = __builtin_amdgcn_mfma_f32_16x16x32_f16(ax[0], wxT[1][ct][0], zero4, 0, 0, 0);
            pz = __builtin_amdgcn_mfma_f32_16x16x32_f16(ax[1], wxT[1][ct][1], pz, 0, 0, 0);
            half4v hz = {(__fp16)fast_tanh(pz[0] + bZ[ct]), (__fp16)fast_tanh(pz[1] + bZ[ct]),
                         (__fp16)fast_tanh(pz[2] + bZ[ct]), (__fp16)fast_tanh(pz[3] + bZ[ct])};
            *(half4v*)&zT[dst][col][kg * 4] = hz;
        }
    };

    // ---- prologue ----
    xload(0);
    if (tid < 128) hbuf[0][tid] = (__fp16)0.0f;   // h0 = 0
    proj(0);                                      // chunk 0 -> buf 0 (own cols)
    xload(1);
    __syncthreads();                              // hbuf zero visible to all waves

    float hn0 = 0.0f, hn1 = 0.0f;
    float oreg0[16], oreg1[16];
    const size_t CPY = (size_t)NB * NT * NH;
    // kh==0 lanes store copy 0; kh==1 lanes store copy 1; kh>=2 store nothing
    float* obase = out + (size_t)b * NT * NH + (kh == 1 ? CPY : 0);

    for (int c = 0; c < 64; ++c) {
        const int cb = c & 1;

        // chunk g/z for this lane's two rows: 8x ds_read_b128 (same-wave data)
        half8 g0a = *(const half8*)&gT[cb][j0][0], g0b = *(const half8*)&gT[cb][j0][8];
        half8 g1a = *(const half8*)&gT[cb][j1][0], g1b = *(const half8*)&gT[cb][j1][8];
        half8 z0a = *(const half8*)&zT[cb][j0][0], z0b = *(const half8*)&zT[cb][j0][8];
        half8 z1a = *(const half8*)&zT[cb][j1][0], z1b = *(const half8*)&zT[cb][j1][8];

        #pragma unroll
        for (int s = 0; s < 16; ++s) {
            const int p = s & 1;
            // h k-slice [32kh, 32kh+32): 4x ds_read_b128 (quad-broadcast)
            half8 ah0 = *(const half8*)&hbuf[p][kh * 32 + 0];
            half8 ah1 = *(const half8*)&hbuf[p][kh * 32 + 8];
            half8 ah2 = *(const half8*)&hbuf[p][kh * 32 + 16];
            half8 ah3 = *(const half8*)&hbuf[p][kh * 32 + 24];

            const float gv0 = (float)(s < 8 ? g0a[s & 7] : g0b[s & 7]);
            const float gv1 = (float)(s < 8 ? g1a[s & 7] : g1b[s & 7]);
            const float zv0 = (float)(s < 8 ? z0a[s & 7] : z0b[s & 7]);
            const float zv1 = (float)(s < 8 ? z1a[s & 7] : z1b[s & 7]);
            const float d0 = zv0 - hn0;       // off-chain vs the dot
            const float d1 = zv1 - hn1;

            // partial dots over this lane's 32-elem slice: 4 chains x depth 4 per j
            float a0 = 0.f, a1 = 0.f, a2 = 0.f, a3 = 0.f;
            float c0 = 0.f, c1 = 0.f, c2 = 0.f, c3 = 0.f;
            #pragma unroll
            for (int blk = 0; blk < 4; ++blk) {
                const half8 hv = blk == 0 ? ah0 : blk == 1 ? ah1 : blk == 2 ? ah2 : ah3;
                const half2v h01 = __builtin_shufflevector(hv, hv, 0, 1);
                const half2v h23 = __builtin_shufflevector(hv, hv, 2, 3);
                const half2v h45 = __builtin_shufflevector(hv, hv, 4, 5);
                const half2v h67 = __builtin_shufflevector(hv, hv, 6, 7);
                a0 = fdot2f(w0[4 * blk + 0], h01, a0);
                a1 = fdot2f(w0[4 * blk + 1], h23, a1);
                a2 = fdot2f(w0[4 * blk + 2], h45, a2);
                a3 = fdot2f(w0[4 * blk + 3], h67, a3);
                c0 = fdot2f(w1[4 * blk + 0], h01, c0);
                c1 = fdot2f(w1[4 * blk + 1], h23, c1);
                c2 = fdot2f(w1[4 * blk + 2], h45, c2);
                c3 = fdot2f(w1[4 * blk + 3], h67, c3);
            }
            // reduce the 4 k-quarters across the lane quad (xor1 then xor2, DPP)
            const float y0 = dpp_xor2_add(dpp_xor1_add((a0 + a1) + (a2 + a3)));
            const float y1 = dpp_xor2_add(dpp_xor1_add((c0 + c1) + (c2 + c3)));

            // tail: K = sigmoid(y + g); h = tanh(h + K*(z - h))
            const float K0 = __builtin_amdgcn_rcpf(1.0f + __expf(-(y0 + gv0)));
            const float K1 = __builtin_amdgcn_rcpf(1.0f + __expf(-(y1 + gv1)));
            hn0 = fast_tanh(__builtin_fmaf(K0, d0, hn0));
            hn1 = fast_tanh(__builtin_fmaf(K1, d1, hn1));

            if (kh == 0) {                        // one kh-quarter publishes h
                hbuf[p ^ 1][j0] = (__fp16)hn0;
                hbuf[p ^ 1][j1] = (__fp16)hn1;
            }
            oreg0[s] = hn0;
            oreg1[s] = hn1;
            fast_barrier();                       // the ONLY sync: h exchange
        }

        // burst-flush outputs (both copies) off the step-latency chain;
        // fire-and-forget VMEM overlapping next chunk's proj + steps
        if (kh < 2) {
            float* po = obase + (size_t)(c * 16) * NH;
            #pragma unroll
            for (int s = 0; s < 16; ++s) {
                po[j0] = oreg0[s];
                po[j1] = oreg1[s];
                po += NH;
            }
        }

        // barrier-free proj of chunk c+1 (same-wave cols; xf loaded 1 chunk ago),
        // then prefetch x chunk c+2
        if (c < 63) {
            proj(cb ^ 1);
            if (c < 62) xload(c + 2);
        }
    }
}

extern "C" void kernel_launch(void* const* d_in, const int* in_sizes, int n_in,
                              void* d_out, int out_size, void* d_ws, size_t ws_size,
                              hipStream_t stream) {
    (void)in_sizes; (void)n_in; (void)d_ws; (void)ws_size; (void)out_size;
    const float* x   = (const float*)d_in[0];
    const float* WxK = (const float*)d_in[1];
    const float* bxK = (const float*)d_in[2];
    const float* Wxz = (const float*)d_in[3];
    const float* bxz = (const float*)d_in[4];
    const float* Whk = (const float*)d_in[5];
    const float* bhk = (const float*)d_in[6];
    float* out = (float*)d_out;

    fused_rnn_v7<<<256, 256, 0, stream>>>(x, WxK, bxK, Wxz, bxz, Whk, bhk, out);
}

// Round 8
// 502.505 us; speedup vs baseline: 1.2082x; 1.2082x over previous
//
#include <hip/hip_runtime.h>
#include <hip/hip_fp16.h>

#define NB 256      // batch
#define NT 1024     // time
#define ND 64       // input dim
#define NH 128      // hidden dim

typedef __fp16 half8 __attribute__((ext_vector_type(8)));
typedef __fp16 half4v __attribute__((ext_vector_type(4)));
typedef float float4v __attribute__((ext_vector_type(4)));

static __device__ __forceinline__ float fast_tanh(float v) {
    float e = __expf(2.0f * v);
    return 1.0f - 2.0f * __builtin_amdgcn_rcpf(e + 1.0f);
}

// lgkm-only barrier: does NOT drain vmcnt (stores / x prefetch keep flying)
static __device__ __forceinline__ void fast_barrier() {
    asm volatile("s_waitcnt lgkmcnt(0)\n\ts_barrier" ::: "memory");
}

// 8 waves (2/SIMD), block = batch. Wave w owns hidden units j in [16w, 16w+16):
// lane l16 = j - 16w holds exactly ONE j (kg = lane>>4 duplicates it 4x -> the
// per-lane serial tail stays minimal, the r7 lesson). Per step the matvec
// y = W_hK·h is 4 MFMAs (A = h broadcast to 16 rows; D col = l16 -> the lane's
// own y lands in reg 0, NO select). Two waves per SIMD fill each other's
// latency shadows (r5 had 75% idle issue slots). g/z are staged TRANSPOSED
// [j][s] by the same wave that reads them (barrier-free proj) and hoisted into
// registers once per chunk -> zero per-step g/z LDS traffic on the lgkm drain.
// Only sync: one lgkm barrier per step for the h exchange.
__global__ __launch_bounds__(512, 1) void fused_rnn_v8(
        const float* __restrict__ x,
        const float* __restrict__ WxK, const float* __restrict__ bxK,
        const float* __restrict__ Wxz, const float* __restrict__ bxz,
        const float* __restrict__ Whk, const float* __restrict__ bhk,
        float* __restrict__ out) {
    __shared__ __align__(16) __fp16 hbuf[2][128];    // h fp16, dbuf per step parity
    __shared__ __align__(16) __fp16 gT[2][128][24];  // (gxK+bxK+bhK)^T: [j][s], 48B rows
    __shared__ __align__(16) __fp16 zT[2][128][24];  // tanh(gxz+bxz)^T: [j][s]

    const int tid = threadIdx.x;
    const int b = blockIdx.x;
    const int w = tid >> 6, lane = tid & 63;
    const int l16 = lane & 15, kg = lane >> 4;
    const int j = w * 16 + l16;              // this lane's single hidden unit

    // ---- W_hK^T B-fragments (4 MFMAs): B[k=kt*32+kg*8+e][n=l16] = Whk[j][k] ----
    half8 whT[4];
    #pragma unroll
    for (int kt = 0; kt < 4; ++kt) {
        const float* p = Whk + (size_t)j * NH + kt * 32 + kg * 8;
        float4v u = *(const float4v*)p, v = *(const float4v*)(p + 4);
        whT[kt] = (half8){(__fp16)u.x, (__fp16)u.y, (__fp16)u.z, (__fp16)u.w,
                          (__fp16)v.x, (__fp16)v.y, (__fp16)v.z, (__fp16)v.w};
    }

    // ---- proj B-fragments (4 MFMAs): rows 16w..16w+16 of WxK / Wxz ----
    half8 wxT[2][2];   // [mat][kt]
    #pragma unroll
    for (int mat = 0; mat < 2; ++mat) {
        const float* W = mat ? Wxz : WxK;
        #pragma unroll
        for (int kt = 0; kt < 2; ++kt) {
            const float* p = W + (size_t)j * ND + kt * 32 + kg * 8;
            float4v u = *(const float4v*)p, v = *(const float4v*)(p + 4);
            wxT[mat][kt] = (half8){(__fp16)u.x, (__fp16)u.y, (__fp16)u.z, (__fp16)u.w,
                                   (__fp16)v.x, (__fp16)v.y, (__fp16)v.z, (__fp16)v.w};
        }
    }
    const float bGK = bxK[j] + bhk[j];       // fold bhK into the staged gate
    const float bZ  = bxz[j];
    const float4v zero4 = {0.f, 0.f, 0.f, 0.f};

    const float* xb = x + (size_t)b * NT * ND;
    float4v xf[4];    // prefetched x chunk A-fragments (f32)

    // load x chunk c: A[row=l16 (timestep)][k=kt*32+kg*8+e]
    auto xload = [&](int c) {
        const float* px = xb + (size_t)c * 16 * 64 + (size_t)l16 * 64;
        #pragma unroll
        for (int kt = 0; kt < 2; ++kt) {
            const float* qp = px + kt * 32 + kg * 8;
            xf[2 * kt]     = *(const float4v*)qp;
            xf[2 * kt + 1] = *(const float4v*)(qp + 4);
        }
    };

    // project staged chunk into this wave's 16 rows of gT/zT[dst] (transposed):
    // 4 MFMAs + 2 packed b64 writes + 4 tanh. Barrier-free (same-wave use).
    auto proj = [&](int dst) {
        half8 ax[2];
        #pragma unroll
        for (int kt = 0; kt < 2; ++kt) {
            float4v u = xf[2 * kt], v = xf[2 * kt + 1];
            ax[kt] = (half8){(__fp16)u.x, (__fp16)u.y, (__fp16)u.z, (__fp16)u.w,
                             (__fp16)v.x, (__fp16)v.y, (__fp16)v.z, (__fp16)v.w};
        }
        // mat 0: gxK (+ folded biases).  D row = kg*4+r = timestep, col = l16 -> j
        float4v pg = __builtin_amdgcn_mfma_f32_16x16x32_f16(ax[0], wxT[0][0], zero4, 0, 0, 0);
        pg = __builtin_amdgcn_mfma_f32_16x16x32_f16(ax[1], wxT[0][1], pg, 0, 0, 0);
        half4v hg = {(__fp16)(pg[0] + bGK), (__fp16)(pg[1] + bGK),
                     (__fp16)(pg[2] + bGK), (__fp16)(pg[3] + bGK)};
        *(half4v*)&gT[dst][j][kg * 4] = hg;
        // mat 1: z = tanh(gxz + bxz)
        float4v pz = __builtin_amdgcn_mfma_f32_16x16x32_f16(ax[0], wxT[1][0], zero4, 0, 0, 0);
        pz = __builtin_amdgcn_mfma_f32_16x16x32_f16(ax[1], wxT[1][1], pz, 0, 0, 0);
        half4v hz = {(__fp16)fast_tanh(pz[0] + bZ), (__fp16)fast_tanh(pz[1] + bZ),
                     (__fp16)fast_tanh(pz[2] + bZ), (__fp16)fast_tanh(pz[3] + bZ)};
        *(half4v*)&zT[dst][j][kg * 4] = hz;
    };

    // ---- prologue ----
    xload(0);
    if (tid < 128) hbuf[0][tid] = (__fp16)0.0f;   // h0 = 0
    proj(0);                                      // chunk 0 -> buf 0 (own rows)
    xload(1);
    __syncthreads();                              // hbuf + staged chunk visible

    float hn = 0.0f;
    float oreg[16];
    const size_t CPY = (size_t)NB * NT * NH;
    // kg==0 lanes store copy 0; kg==1 lanes store copy 1; kg>=2 store nothing
    float* obase = out + (size_t)b * NT * NH + (kg == 1 ? CPY : 0);

    for (int c = 0; c < 64; ++c) {
        const int cb = c & 1;

        // hoist this chunk's g/z into regs: 4x ds_read_b128, off the step chain
        half8 gA = *(const half8*)&gT[cb][j][0];
        half8 gB = *(const half8*)&gT[cb][j][8];
        half8 zA = *(const half8*)&zT[cb][j][0];
        half8 zB = *(const half8*)&zT[cb][j][8];

        #pragma unroll
        for (int s = 0; s < 16; ++s) {
            const int p = s & 1;
            // h A-fragments: broadcast reads (addr depends only on kg) — 4x b128
            half8 ah0 = *(const half8*)&hbuf[p][0 * 32 + kg * 8];
            half8 ah1 = *(const half8*)&hbuf[p][1 * 32 + kg * 8];
            half8 ah2 = *(const half8*)&hbuf[p][2 * 32 + kg * 8];
            half8 ah3 = *(const half8*)&hbuf[p][3 * 32 + kg * 8];

            const float gv = (float)(s < 8 ? gA[s & 7] : gB[s & 7]);
            const float zv = (float)(s < 8 ? zA[s & 7] : zB[s & 7]);
            const float d = zv - hn;          // off-chain vs the dot

            // y = W_hK·h : 4 MFMAs, two 2-deep chains; D col=l16 -> own j, reg 0
            float4v aA = __builtin_amdgcn_mfma_f32_16x16x32_f16(ah0, whT[0], zero4, 0, 0, 0);
            float4v aB = __builtin_amdgcn_mfma_f32_16x16x32_f16(ah2, whT[2], zero4, 0, 0, 0);
            aA = __builtin_amdgcn_mfma_f32_16x16x32_f16(ah1, whT[1], aA, 0, 0, 0);
            aB = __builtin_amdgcn_mfma_f32_16x16x32_f16(ah3, whT[3], aB, 0, 0, 0);
            const float y = aA[0] + aB[0];

            // tail: K = sigmoid(y + g); h = tanh(h + K*(z - h))
            const float K = __builtin_amdgcn_rcpf(1.0f + __expf(-(y + gv)));
            hn = fast_tanh(__builtin_fmaf(K, d, hn));
            oreg[s] = hn;

            if (kg == 0) hbuf[p ^ 1][j] = (__fp16)hn;   // publish own j
            fast_barrier();                   // the ONLY sync: h exchange
        }

        // burst-flush outputs (both copies) off the step chain; fire-and-forget
        if (kg < 2) {
            float* po = obase + (size_t)(c * 16) * NH;
            #pragma unroll
            for (int s = 0; s < 16; ++s) {
                po[j] = oreg[s];
                po += NH;
            }
        }

        // barrier-free proj of chunk c+1 (same-wave rows; xf loaded 1 chunk ago),
        // then prefetch x chunk c+2
        if (c < 63) {
            proj(cb ^ 1);
            if (c < 62) xload(c + 2);
        }
    }
}

extern "C" void kernel_launch(void* const* d_in, const int* in_sizes, int n_in,
                              void* d_out, int out_size, void* d_ws, size_t ws_size,
                              hipStream_t stream) {
    (void)in_sizes; (void)n_in; (void)d_ws; (void)ws_size; (void)out_size;
    const float* x   = (const float*)d_in[0];
    const float* WxK = (const float*)d_in[1];
    const float* bxK = (const float*)d_in[2];
    const float* Wxz = (const float*)d_in[3];
    const float* bxz = (const float*)d_in[4];
    const float* Whk = (const float*)d_in[5];
    const float* bhk = (const float*)d_in[6];
    float* out = (float*)d_out;

    fused_rnn_v8<<<256, 512, 0, stream>>>(x, WxK, bxK, Wxz, bxz, Whk, bhk, out);
}